// Round 2
// baseline (360.723 us; speedup 1.0000x reference)
//
#include <hip/hip_runtime.h>
#include <hip/hip_bf16.h>
#include <stdint.h>

// Problem constants (B=4096, D=2048, K=8, H2=64)
#define NB 4096
#define ND 2048
#define NK 8
#define NH 64

// GEMM tile config: 128x128 tile, BK=32, 16x16x32 bf16 MFMA, fused fp32->bf16
#define BM 128
#define BN 128
#define BK 32
#define LDA 40          // padded LDS row stride in bf16 elements (80 B: bank-spread)
#define MAX_ROWS 5120   // 4096 + padding worst case (40 tiles * 128)
#define MAX_TILES 40

typedef __bf16 bf16;
typedef __bf16 bf16x8 __attribute__((ext_vector_type(8)));
typedef float floatx4 __attribute__((ext_vector_type(4)));

// Workspace layout (bytes): only small metadata now.
#define OFF_KIDX   0u          // 4096 int
#define OFF_ORDER  16384u      // 5120 int (-1 = padding row)
#define OFF_META   40960u      // [0]=n_mtiles, [1..40]=tile branch, [41..80]=tile row0

// ---------------------------------------------------------------------------
// Kernel 1: single-block prep. Branch index per sample, per-branch counts,
// padded sample ordering, M-tile table, fc2-side scalar c2[k], out init.
// ---------------------------------------------------------------------------
__global__ void prep_kernel(const float* __restrict__ intention,
                            const float* __restrict__ W2,
                            const float* __restrict__ b2,
                            const float* __restrict__ W3,
                            const float* __restrict__ b3,
                            int* __restrict__ kidx,
                            int* __restrict__ order,
                            int* __restrict__ meta,
                            float* __restrict__ out)
{
    __shared__ int cnt[NK];
    __shared__ int cur[NK];
    __shared__ float c2s[NK];
    const int tid = threadIdx.x;

    if (tid < NK) cnt[tid] = 0;
    for (int i = tid; i < MAX_ROWS; i += 256) order[i] = -1;
    __syncthreads();

    // branch argmax (one-hot: the entry > 0.5)
    for (int b = tid; b < NB; b += 256) {
        const float* row = intention + b * NK;
        int k = 0;
#pragma unroll
        for (int j = 1; j < NK; j++)
            if (row[j] > 0.5f) k = j;
        kidx[b] = k;
        atomicAdd(&cnt[k], 1);
    }
    __syncthreads();

    if (tid == 0) {
        int running = 0, nt = 0;
        for (int k = 0; k < NK; k++) {
            cur[k] = running;
            int ntile = (cnt[k] + BM - 1) / BM;
            for (int t = 0; t < ntile; t++) {
                meta[1 + nt] = k;
                meta[1 + MAX_TILES + nt] = running + t * BM;
                nt++;
            }
            running += ntile * BM;
        }
        meta[0] = nt;
    }
    __syncthreads();

    // scatter sample indices grouped by branch
    for (int b = tid; b < NB; b += 256) {
        int k = kidx[b];
        int pos = atomicAdd(&cur[k], 1);
        order[pos] = b;
    }

    // c2[k] = b3 + sum_h relu(W2[h,k] + b2[h]) * W3[D + h]
    if (tid < NK) {
        float s = b3[0];
        for (int h = 0; h < NH; h++) {
            float v = W2[h * NK + tid] + b2[h];
            if (v > 0.f) s += v * W3[ND + h];
        }
        c2s[tid] = s;
    }
    __syncthreads();

    for (int b = tid; b < NB; b += 256)
        out[b] = c2s[kidx[b]];
}

// ---------------------------------------------------------------------------
// Kernel 2: fused gather + convert + per-branch bf16 GEMM + epilogue.
// C_tile = x[order rows] . W1[branch-slice]^T; staging loads fp32 and
// converts to bf16 into padded LDS (stride 40 elems -> 2-way banks max).
// Epilogue: +b1, relu, *W3, 16-lane shuffle reduce, atomicAdd into out.
// ---------------------------------------------------------------------------
__device__ inline void cvt_store16(bf16* dst, float4 a, float4 c) {
    bf16x8 v;
    v[0] = (bf16)a.x; v[1] = (bf16)a.y; v[2] = (bf16)a.z; v[3] = (bf16)a.w;
    v[4] = (bf16)c.x; v[5] = (bf16)c.y; v[6] = (bf16)c.z; v[7] = (bf16)c.w;
    *(bf16x8*)dst = v;
}

__global__ void gemm_kernel(const float* __restrict__ x,
                            const float* __restrict__ W1,
                            const int* __restrict__ order,
                            const int* __restrict__ meta,
                            const float* __restrict__ b1,
                            const float* __restrict__ W3,
                            float* __restrict__ out)
{
    const int n_mt = meta[0];
    const int mt = blockIdx.y;
    if (mt >= n_mt) return;
    const int kbr = meta[1 + mt];
    const int row0 = meta[1 + MAX_TILES + mt];
    const int col0 = blockIdx.x * BN;

    __shared__ int rowb[BM];
    __shared__ bf16 As[BM * LDA];   // 10240 B
    __shared__ bf16 Bs[BN * LDA];   // 10240 B

    const int tid = threadIdx.x;
    const int lane = tid & 63;
    const int wid = tid >> 6;
    const int wm = wid >> 1;       // 0..1
    const int wn = wid & 1;        // 0..1

    if (tid < BM) rowb[tid] = order[row0 + tid];
    __syncthreads();

    // staging assignment: thread covers (srow, scol..scol+7) for two row
    // halves r in {0,1} (rows srow and 64+srow).
    const int srow = tid >> 2;            // 0..63
    const int scol = (tid & 3) * 8;       // fp32/bf16 element offset

    const int a0 = rowb[srow];
    const int a1 = rowb[64 + srow];
    const float* pa0 = x + (size_t)(a0 < 0 ? 0 : a0) * ND + scol;
    const float* pa1 = x + (size_t)(a1 < 0 ? 0 : a1) * ND + scol;
    const float* pb0 = W1 + ((size_t)(col0 + srow) * NK + kbr) * ND + scol;
    const float* pb1 = W1 + ((size_t)(col0 + 64 + srow) * NK + kbr) * ND + scol;
    bf16* wa0 = As + srow * LDA + scol;
    bf16* wa1 = As + (64 + srow) * LDA + scol;
    bf16* wb0 = Bs + srow * LDA + scol;
    bf16* wb1 = Bs + (64 + srow) * LDA + scol;

    floatx4 zero = {0.f, 0.f, 0.f, 0.f};
    floatx4 acc[4][4];
#pragma unroll
    for (int i = 0; i < 4; i++)
#pragma unroll
        for (int j = 0; j < 4; j++) acc[i][j] = zero;

    const int qk = (lane >> 4) * 8;       // k-offset within fragment
    const int mrow = lane & 15;

    for (int kk = 0; kk < ND; kk += BK) {
        // load fp32, convert, stage to LDS
        float4 va0 = *(const float4*)(pa0 + kk);
        float4 va0b = *(const float4*)(pa0 + kk + 4);
        float4 va1 = *(const float4*)(pa1 + kk);
        float4 va1b = *(const float4*)(pa1 + kk + 4);
        float4 vb0 = *(const float4*)(pb0 + kk);
        float4 vb0b = *(const float4*)(pb0 + kk + 4);
        float4 vb1 = *(const float4*)(pb1 + kk);
        float4 vb1b = *(const float4*)(pb1 + kk + 4);
        cvt_store16(wa0, va0, va0b);
        cvt_store16(wa1, va1, va1b);
        cvt_store16(wb0, vb0, vb0b);
        cvt_store16(wb1, vb1, vb1b);
        __syncthreads();

        bf16x8 af[4], bfv[4];
#pragma unroll
        for (int i = 0; i < 4; i++) {
            af[i]  = *(const bf16x8*)(As + (wm * 64 + i * 16 + mrow) * LDA + qk);
            bfv[i] = *(const bf16x8*)(Bs + (wn * 64 + i * 16 + mrow) * LDA + qk);
        }
#pragma unroll
        for (int i = 0; i < 4; i++)
#pragma unroll
            for (int j = 0; j < 4; j++)
                acc[i][j] = __builtin_amdgcn_mfma_f32_16x16x32_bf16(
                    af[i], bfv[j], acc[i][j], 0, 0, 0);
        __syncthreads();
    }

    // Epilogue. C/D layout: col = lane&15, row = (lane>>4)*4 + reg.
    const int colq = lane & 15;
    const int quad = lane >> 4;
    float bias[4], w3v[4];
#pragma unroll
    for (int j = 0; j < 4; j++) {
        int d = col0 + wn * 64 + j * 16 + colq;
        bias[j] = b1[d * NK + kbr];
        w3v[j] = W3[d];
    }
#pragma unroll
    for (int i = 0; i < 4; i++) {
#pragma unroll
        for (int r = 0; r < 4; r++) {
            float s = 0.f;
#pragma unroll
            for (int j = 0; j < 4; j++) {
                float v = acc[i][j][r] + bias[j];
                s += (v > 0.f) ? v * w3v[j] : 0.f;
            }
#pragma unroll
            for (int m = 1; m < 16; m <<= 1) s += __shfl_xor(s, m, 64);
            if (colq == 0) {
                int b = rowb[wm * 64 + i * 16 + quad * 4 + r];
                if (b >= 0) atomicAdd(out + b, s);
            }
        }
    }
}

// ---------------------------------------------------------------------------
extern "C" void kernel_launch(void* const* d_in, const int* in_sizes, int n_in,
                              void* d_out, int out_size, void* d_ws, size_t ws_size,
                              hipStream_t stream)
{
    const float* x         = (const float*)d_in[0];
    const float* intention = (const float*)d_in[1];
    const float* W1        = (const float*)d_in[2];
    const float* b1        = (const float*)d_in[3];
    const float* W2        = (const float*)d_in[4];
    const float* b2        = (const float*)d_in[5];
    const float* W3        = (const float*)d_in[6];
    const float* b3        = (const float*)d_in[7];
    float* out = (float*)d_out;

    char* ws = (char*)d_ws;
    int*  kidx  = (int*)(ws + OFF_KIDX);
    int*  order = (int*)(ws + OFF_ORDER);
    int*  meta  = (int*)(ws + OFF_META);

    prep_kernel<<<dim3(1), dim3(256), 0, stream>>>(
        intention, W2, b2, W3, b3, kidx, order, meta, out);
    gemm_kernel<<<dim3(ND / BN, MAX_TILES), dim3(256), 0, stream>>>(
        x, W1, order, meta, b1, W3, out);
}